// Round 1
// 1060.224 us; speedup vs baseline: 1.0180x; 1.0180x over previous
//
#include <hip/hip_runtime.h>
#include <math.h>

// SmartMoEFFN: top-2 MoE with folded router.
// B=4 S=2048 D=1024 H=4096 E=8 TOPK=2. Tokens T=8192, pairs=16384.
// Workspace need: ~281 MB (xbf16 16M + W1t 64M + W2t 64M + h 142.6M + lists).

typedef unsigned short u16;
typedef __attribute__((ext_vector_type(8))) short short8_t;
typedef __attribute__((ext_vector_type(4))) float f32x4;

#define TOKENS 8192
#define DDIM 1024
#define HDIM 4096
#define NEXP 8
#define ECAP 8192           // max tokens per expert (padded region fits exactly)
#define MAX_SLOTS 136       // sum ceil(n_e/128) <= 16384/128 + 8
#define NBINS 64            // aux-loss accumulation bins (atomic contention relief)

struct __align__(8) us4 { u16 x, y, z, w; };

__device__ __forceinline__ u16 f2bf(float f) {
  unsigned int u = __float_as_uint(f);
  u += 0x7fffu + ((u >> 16) & 1u);   // RTNE
  return (u16)(u >> 16);
}

__device__ __forceinline__ void gload_lds16(const void* g, void* l) {
  __builtin_amdgcn_global_load_lds((const __attribute__((address_space(1))) void*)g,
                                   (__attribute__((address_space(3))) void*)l, 16, 0, 0);
}

// ---------------- fp32 -> bf16 flat convert (x) ----------------
__global__ void cvt_bf16_kernel(const float* __restrict__ src, u16* __restrict__ dst, long n) {
  long i = ((long)blockIdx.x * 256 + threadIdx.x) * 4;
  if (i < n) {
    float4 v = *(const float4*)&src[i];
    us4 o; o.x = f2bf(v.x); o.y = f2bf(v.y); o.z = f2bf(v.z); o.w = f2bf(v.w);
    *(us4*)&dst[i] = o;
  }
}

// ---------------- fp32 [R][C] -> bf16 [C][R] per expert (blockIdx.z) ----------------
__global__ void transpose_cvt_kernel(const float* __restrict__ src, u16* __restrict__ dst,
                                     int R, int C) {
  __shared__ float tile[32][33];
  size_t mat = (size_t)R * C;
  const float* s = src + (size_t)blockIdx.z * mat;
  u16* d = dst + (size_t)blockIdx.z * mat;
  int r0 = blockIdx.y * 32, c0 = blockIdx.x * 32;
  int tr = threadIdx.x >> 3, tc = (threadIdx.x & 7) * 4;
  float4 v = *(const float4*)&s[(size_t)(r0 + tr) * C + (c0 + tc)];
  tile[tr][tc + 0] = v.x; tile[tr][tc + 1] = v.y;
  tile[tr][tc + 2] = v.z; tile[tr][tc + 3] = v.w;
  __syncthreads();
  int oc = tr, orr = tc;  // output row (c-dim), output col start (r-dim)
  us4 o;
  o.x = f2bf(tile[orr + 0][oc]); o.y = f2bf(tile[orr + 1][oc]);
  o.z = f2bf(tile[orr + 2][oc]); o.w = f2bf(tile[orr + 3][oc]);
  *(us4*)&d[(size_t)(c0 + oc) * R + (r0 + orr)] = o;
}

// ---------------- crW[d][e] = sum_k ctx_W[d][k] * r_W[k][e] ----------------
__global__ void crw_kernel(const float* __restrict__ ctxW, const float* __restrict__ rW,
                           float* __restrict__ crW) {
  __shared__ float lbuf[32];
  int d = blockIdx.x, tid = threadIdx.x;
  float acc[8] = {0,0,0,0,0,0,0,0};
  for (int k = tid; k < DDIM; k += 256) {
    float c = ctxW[(size_t)d * DDIM + k];
    float4 r0 = *(const float4*)&rW[k * 8];
    float4 r1 = *(const float4*)&rW[k * 8 + 4];
    acc[0] += c * r0.x; acc[1] += c * r0.y; acc[2] += c * r0.z; acc[3] += c * r0.w;
    acc[4] += c * r1.x; acc[5] += c * r1.y; acc[6] += c * r1.z; acc[7] += c * r1.w;
  }
  int w = tid >> 6, lane = tid & 63;
  #pragma unroll
  for (int off = 32; off; off >>= 1) {
    #pragma unroll
    for (int e = 0; e < 8; e++) acc[e] += __shfl_down(acc[e], off);
  }
  if (lane == 0) {
    #pragma unroll
    for (int e = 0; e < 8; e++) lbuf[w * 8 + e] = acc[e];
  }
  __syncthreads();
  if (tid == 0) {
    #pragma unroll
    for (int e = 0; e < 8; e++)
      crW[d * 8 + e] = lbuf[e] + lbuf[8 + e] + lbuf[16 + e] + lbuf[24 + e];
  }
}

// ---------------- cbase[b][e] = (ctx_b + quality[b]*qW + q_b) . rW[:,e] + r_b[e] ----------------
__global__ void cbase_kernel(const float* __restrict__ ctx_b, const float* __restrict__ qW,
                             const float* __restrict__ q_b, const float* __restrict__ quality,
                             const float* __restrict__ rW, const float* __restrict__ r_b,
                             float* __restrict__ cbase) {
  __shared__ float lbuf[32];
  int b = blockIdx.x, tid = threadIdx.x;
  float qv = quality[b];
  float acc[8] = {0,0,0,0,0,0,0,0};
  for (int d = tid; d < DDIM; d += 256) {
    float base = ctx_b[d] + qv * qW[d] + q_b[d];
    float4 r0 = *(const float4*)&rW[d * 8];
    float4 r1 = *(const float4*)&rW[d * 8 + 4];
    acc[0] += base * r0.x; acc[1] += base * r0.y; acc[2] += base * r0.z; acc[3] += base * r0.w;
    acc[4] += base * r1.x; acc[5] += base * r1.y; acc[6] += base * r1.z; acc[7] += base * r1.w;
  }
  int w = tid >> 6, lane = tid & 63;
  #pragma unroll
  for (int off = 32; off; off >>= 1) {
    #pragma unroll
    for (int e = 0; e < 8; e++) acc[e] += __shfl_down(acc[e], off);
  }
  if (lane == 0) {
    #pragma unroll
    for (int e = 0; e < 8; e++) lbuf[w * 8 + e] = acc[e];
  }
  __syncthreads();
  if (tid == 0) {
    #pragma unroll
    for (int e = 0; e < 8; e++)
      cbase[b * 8 + e] = lbuf[e] + lbuf[8 + e] + lbuf[16 + e] + lbuf[24 + e] + r_b[e];
  }
}

// ---------------- router: LN stats + 16 dots + top2 + aux partials + bucketing ----------------
__global__ void router_kernel(const float* __restrict__ x, const float* __restrict__ ctx,
    const float* __restrict__ rn_g, const float* __restrict__ rn_b,
    const float* __restrict__ cn_g, const float* __restrict__ cn_b,
    const float* __restrict__ rW, const float* __restrict__ crW,
    const float* __restrict__ cbase, const float* __restrict__ temp_p,
    int* __restrict__ token_list, float* __restrict__ gate_list,
    int* __restrict__ counts, float* __restrict__ aux) {
  __shared__ float rbuf[16];
  __shared__ float lbuf[32];
  const int t = blockIdx.x;
  const int tid = threadIdx.x;
  const int b = t >> 11;
  const float* xr = x + (size_t)t * DDIM;
  const float* cr = ctx + (size_t)t * DDIM;
  float xv[4], cv[4];
  #pragma unroll
  for (int k = 0; k < 4; k++) { int d = tid + k * 256; xv[k] = xr[d]; cv[k] = cr[d]; }
  float sx = 0, sxx = 0, sc = 0, scc = 0;
  #pragma unroll
  for (int k = 0; k < 4; k++) {
    sx += xv[k]; sxx += xv[k] * xv[k];
    sc += cv[k]; scc += cv[k] * cv[k];
  }
  #pragma unroll
  for (int off = 32; off; off >>= 1) {
    sx += __shfl_down(sx, off); sxx += __shfl_down(sxx, off);
    sc += __shfl_down(sc, off); scc += __shfl_down(scc, off);
  }
  int w = tid >> 6, lane = tid & 63;
  if (lane == 0) {
    rbuf[w * 4 + 0] = sx; rbuf[w * 4 + 1] = sxx;
    rbuf[w * 4 + 2] = sc; rbuf[w * 4 + 3] = scc;
  }
  __syncthreads();
  sx  = rbuf[0] + rbuf[4] + rbuf[8]  + rbuf[12];
  sxx = rbuf[1] + rbuf[5] + rbuf[9]  + rbuf[13];
  sc  = rbuf[2] + rbuf[6] + rbuf[10] + rbuf[14];
  scc = rbuf[3] + rbuf[7] + rbuf[11] + rbuf[15];
  const float invD = 1.f / 1024.f;
  float mx = sx * invD, vx = sxx * invD - mx * mx;
  float mc = sc * invD, vc = scc * invD - mc * mc;
  float rsx = rsqrtf(vx + 1e-5f), rsc = rsqrtf(vc + 1e-5f);
  float acc[8] = {0,0,0,0,0,0,0,0};
  #pragma unroll
  for (int k = 0; k < 4; k++) {
    int d = tid + k * 256;
    float lx = (xv[k] - mx) * rsx * rn_g[d] + rn_b[d];
    float lc = (cv[k] - mc) * rsc * cn_g[d] + cn_b[d];
    float4 r0 = *(const float4*)&rW[d * 8];
    float4 r1 = *(const float4*)&rW[d * 8 + 4];
    float4 c0 = *(const float4*)&crW[d * 8];
    float4 c1 = *(const float4*)&crW[d * 8 + 4];
    acc[0] += lx * r0.x + lc * c0.x; acc[1] += lx * r0.y + lc * c0.y;
    acc[2] += lx * r0.z + lc * c0.z; acc[3] += lx * r0.w + lc * c0.w;
    acc[4] += lx * r1.x + lc * c1.x; acc[5] += lx * r1.y + lc * c1.y;
    acc[6] += lx * r1.z + lc * c1.z; acc[7] += lx * r1.w + lc * c1.w;
  }
  #pragma unroll
  for (int off = 32; off; off >>= 1) {
    #pragma unroll
    for (int e = 0; e < 8; e++) acc[e] += __shfl_down(acc[e], off);
  }
  if (lane == 0) {
    #pragma unroll
    for (int e = 0; e < 8; e++) lbuf[w * 8 + e] = acc[e];
  }
  __syncthreads();
  if (tid == 0) {
    float inv_t = 1.f / fmaxf(temp_p[0], 0.25f);
    float lg[8];
    #pragma unroll
    for (int e = 0; e < 8; e++)
      lg[e] = (lbuf[e] + lbuf[8 + e] + lbuf[16 + e] + lbuf[24 + e] + cbase[b * 8 + e]) * inv_t;
    int i0 = 0;
    #pragma unroll
    for (int e = 1; e < 8; e++) if (lg[e] > lg[i0]) i0 = e;
    int i1 = -1;
    #pragma unroll
    for (int e = 0; e < 8; e++) if (e != i0 && (i1 < 0 || lg[e] > lg[i1])) i1 = e;
    float e1v = __expf(lg[i1] - lg[i0]);
    float g0 = 1.f / (1.f + e1v), g1 = e1v / (1.f + e1v);
    float m8 = lg[i0];
    float pe[8], se = 0.f;
    #pragma unroll
    for (int e = 0; e < 8; e++) { pe[e] = expf(lg[e] - m8); se += pe[e]; }
    float inv_se = 1.f / se;
    float z = m8 + logf(se);
    float entc = 0.f;
    #pragma unroll
    for (int e = 0; e < 8; e++) {
      float p = pe[e] * inv_se;
      entc -= p * logf(fmaxf(p, 1e-9f));
    }
    int bin = (t & (NBINS - 1)) * 12;
    #pragma unroll
    for (int e = 0; e < 8; e++) atomicAdd(&aux[bin + e], pe[e] * inv_se);
    atomicAdd(&aux[bin + 8], z * z);
    atomicAdd(&aux[bin + 9], entc);
    int p0 = atomicAdd(&counts[i0], 1);
    token_list[i0 * ECAP + p0] = t; gate_list[i0 * ECAP + p0] = g0;
    int p1 = atomicAdd(&counts[i1], 1);
    token_list[i1 * ECAP + p1] = t; gate_list[i1 * ECAP + p1] = g1;
  }
}

// ---------------- finalize: tile table, list padding, aux scalars (PARALLEL) ----------------
// Old version was single-threaded: ~1300 dependent global ops => ~100-300us serial bubble.
// Now: 256 threads; table slots, padding, and aux columns all parallel.
__global__ void finalize_kernel(const int* __restrict__ counts, const float* __restrict__ aux,
                                int* __restrict__ token_list, float* __restrict__ gate_list,
                                int4* __restrict__ table, float* __restrict__ out_scalars) {
  __shared__ int scnt[NEXP], stl[NEXP], sbase[NEXP];
  __shared__ float sred[16];
  const int tid = threadIdx.x;
  if (tid < NEXP) {
    int c = counts[tid];
    scnt[tid] = c;
    stl[tid] = (c + 127) >> 7;
  }
  __syncthreads();
  if (tid == 0) {
    int s = 0;
    for (int e = 0; e < NEXP; e++) { sbase[e] = s; s += stl[e]; }
  }
  __syncthreads();
  // tile table: each thread owns slots tid, tid+256, ...
  for (int slot = tid; slot < MAX_SLOTS; slot += 256) {
    int4 v = make_int4(-1, 0, 0, 0);
    #pragma unroll
    for (int e = 0; e < NEXP; e++) {
      int rel = slot - sbase[e];
      if (rel >= 0 && rel < stl[e]) {
        int rv = scnt[e] - rel * 128;
        if (rv > 128) rv = 128;
        v = make_int4(e, rel * 128, rv, 0);
      }
    }
    table[slot] = v;
  }
  // list padding: at most 127 pad entries per expert -> 8*128 candidate slots
  for (int idx = tid; idx < NEXP * 128; idx += 256) {
    int e = idx >> 7, p = idx & 127;
    int pos = scnt[e] + p;
    if (pos < stl[e] * 128) {
      token_list[e * ECAP + pos] = 0;
      gate_list[e * ECAP + pos] = 0.f;
    }
  }
  // aux reduction: columns 0..7 importance sums, 8 = z^2 sum, 9 = entropy sum
  if (tid < 10) {
    float s = 0.f;
    #pragma unroll 8
    for (int bn = 0; bn < NBINS; bn++) s += aux[bn * 12 + tid];
    sred[tid] = s;
  }
  __syncthreads();
  if (tid == 0) {
    float lb = 0.f;
    #pragma unroll
    for (int e = 0; e < NEXP; e++) {
      float im = sred[e] * (1.f / 8192.f);
      float dd = im - 0.125f;
      lb += dd * dd;
    }
    lb *= (1.f / 8.f);
    float rz = sred[8] * (1.f / 8192.f);
    float ent = sred[9] * (1.f / 8192.f);
    out_scalars[0] = lb;
    out_scalars[1] = rz;
    out_scalars[2] = ent;
    out_scalars[3] = lb + 0.001f * rz - 0.001f * ent;
  }
}

// ---------------- MFMA GEMM, 128x128 tile, BK=64, 4 waves ----------------
// MODE 0: h = gelu(gather(xbf) @ W1t[e]^T + b1[e]) -> bf16 h_out, K=1024, N=4096
// MODE 1: out[tok] += gate * (h @ W2t[e]^T + b2[e]) via atomicAdd, K=4096, N=1024
// launch_bounds min-waves/EU: 2 -> 3 (occupancy probe; 84 arch VGPR + 64 acc fits 3/EU)
template <int MODE>
__launch_bounds__(256, 3)
__global__ void moe_gemm_kernel(const u16* __restrict__ Asrc, const u16* __restrict__ Bt,
    const float* __restrict__ bias, const int* __restrict__ token_list,
    const float* __restrict__ gate_list, const int4* __restrict__ table,
    u16* __restrict__ h_out, float* __restrict__ out) {
  constexpr int KD = (MODE == 0) ? DDIM : HDIM;
  constexpr int ND = (MODE == 0) ? HDIM : DDIM;
  const int slot = blockIdx.y;
  const int4 tb = table[slot];
  const int e = tb.x;
  if (e < 0) return;
  const int row0 = tb.y, rv = tb.z;
  const int n0 = blockIdx.x * 128;
  const int tid = threadIdx.x;
  const int lane = tid & 63, w = tid >> 6;

  __shared__ __align__(16) u16 As[128 * 64];
  __shared__ __align__(16) u16 Bs[128 * 64];

  const u16* aptr[4];
  const u16* bptr[4];
  const u16* bbase = Bt + (size_t)e * ((size_t)ND * KD);
  #pragma unroll
  for (int i = 0; i < 4; i++) {
    int q = i * 256 + tid;
    int row = q >> 3, ch = q & 7;
    size_t abase;
    if (MODE == 0) {
      int tok = token_list[e * ECAP + row0 + row];
      abase = (size_t)tok * KD;
    } else {
      abase = ((size_t)slot * 128 + row) * (size_t)KD;
    }
    aptr[i] = Asrc + abase + ch * 8;
    bptr[i] = bbase + (size_t)(n0 + row) * KD + ch * 8;
  }

  f32x4 acc[4][4];
  #pragma unroll
  for (int i = 0; i < 4; i++) {
    #pragma unroll
    for (int j = 0; j < 4; j++) acc[i][j] = (f32x4){0.f, 0.f, 0.f, 0.f};
  }

  const int lr = lane & 15, quad = lane >> 4;
  const int wm = (w & 1) * 64, wn = (w >> 1) * 64;

  for (int k0 = 0; k0 < KD; k0 += 64) {
    #pragma unroll
    for (int i = 0; i < 4; i++) {
      gload_lds16(aptr[i] + k0, &As[(i * 256 + tid) * 8]);
      gload_lds16(bptr[i] + k0, &Bs[(i * 256 + tid) * 8]);
    }
    __syncthreads();
    #pragma unroll
    for (int kk = 0; kk < 2; kk++) {
      short8_t a[4], b[4];
      #pragma unroll
      for (int i = 0; i < 4; i++)
        a[i] = *(const short8_t*)&As[(wm + i * 16 + lr) * 64 + kk * 32 + quad * 8];
      #pragma unroll
      for (int j = 0; j < 4; j++)
        b[j] = *(const short8_t*)&Bs[(wn + j * 16 + lr) * 64 + kk * 32 + quad * 8];
      #pragma unroll
      for (int i = 0; i < 4; i++) {
        #pragma unroll
        for (int j = 0; j < 4; j++)
          acc[i][j] = __builtin_amdgcn_mfma_f32_16x16x32_bf16(a[i], b[j], acc[i][j], 0, 0, 0);
      }
    }
    __syncthreads();
  }

  float bcol[4];
  #pragma unroll
  for (int j = 0; j < 4; j++) bcol[j] = bias[e * ND + n0 + wn + j * 16 + lr];

  if constexpr (MODE == 0) {
    #pragma unroll
    for (int i = 0; i < 4; i++) {
      #pragma unroll
      for (int r = 0; r < 4; r++) {
        int row = wm + i * 16 + quad * 4 + r;
        size_t ro = ((size_t)slot * 128 + row) * (size_t)HDIM;
        #pragma unroll
        for (int j = 0; j < 4; j++) {
          int col = n0 + wn + j * 16 + lr;
          float v = acc[i][j][r] + bcol[j];
          v = 0.5f * v * (1.f + erff(v * 0.70710678118654752f));
          h_out[ro + col] = f2bf(v);
        }
      }
    }
  } else {
    #pragma unroll
    for (int i = 0; i < 4; i++) {
      #pragma unroll
      for (int r = 0; r < 4; r++) {
        int row = wm + i * 16 + quad * 4 + r;
        if (row < rv) {
          int tok = token_list[e * ECAP + row0 + row];
          float g = gate_list[e * ECAP + row0 + row];
          float* orow = out + (size_t)tok * DDIM;
          #pragma unroll
          for (int j = 0; j < 4; j++) {
            int col = n0 + wn + j * 16 + lr;
            atomicAdd(&orow[col], g * (acc[i][j][r] + bcol[j]));
          }
        }
      }
    }
  }
}

extern "C" void kernel_launch(void* const* d_in, const int* in_sizes, int n_in,
                              void* d_out, int out_size, void* d_ws, size_t ws_size,
                              hipStream_t stream) {
  const float* x      = (const float*)d_in[0];
  const float* ctx    = (const float*)d_in[1];
  const float* qual   = (const float*)d_in[2];
  const float* rn_g   = (const float*)d_in[3];
  const float* rn_b   = (const float*)d_in[4];
  const float* cn_g   = (const float*)d_in[5];
  const float* cn_b   = (const float*)d_in[6];
  const float* ctx_W  = (const float*)d_in[7];
  const float* ctx_b  = (const float*)d_in[8];
  const float* q_W    = (const float*)d_in[9];
  const float* q_b    = (const float*)d_in[10];
  const float* r_W    = (const float*)d_in[11];
  const float* r_b    = (const float*)d_in[12];
  const float* temp   = (const float*)d_in[13];
  const float* W1     = (const float*)d_in[14];
  const float* b1     = (const float*)d_in[15];
  const float* W2     = (const float*)d_in[16];
  const float* b2     = (const float*)d_in[17];
  float* out = (float*)d_out;

  char* ws = (char*)d_ws;
  size_t o = 0;
  auto alloc = [&](size_t bytes) { void* p = ws + o; o += (bytes + 255) & ~(size_t)255; return p; };
  u16*   xbf        = (u16*)alloc((size_t)TOKENS * DDIM * 2);
  u16*   W1t        = (u16*)alloc((size_t)NEXP * HDIM * DDIM * 2);
  u16*   W2t        = (u16*)alloc((size_t)NEXP * DDIM * HDIM * 2);
  u16*   hbuf       = (u16*)alloc((size_t)MAX_SLOTS * 128 * HDIM * 2);
  float* crW        = (float*)alloc(DDIM * 8 * 4);
  float* cb         = (float*)alloc(32 * 4);
  int*   token_list = (int*)alloc(NEXP * ECAP * 4);
  float* gate_list  = (float*)alloc(NEXP * ECAP * 4);
  int*   counts     = (int*)alloc((8 + NBINS * 12) * 4);  // counts[8] then aux bins
  float* aux        = (float*)(counts + 8);
  int4*  table      = (int4*)alloc(MAX_SLOTS * 16);
  (void)ws_size; (void)n_in; (void)in_sizes;

  // zero: out (atomic target + scalar slots), counts+aux bins
  (void)hipMemsetAsync(d_out, 0, (size_t)out_size * 4, stream);
  (void)hipMemsetAsync(counts, 0, (8 + NBINS * 12) * 4, stream);

  cvt_bf16_kernel<<<(TOKENS * DDIM) / 1024, 256, 0, stream>>>(x, xbf, (long)TOKENS * DDIM);
  transpose_cvt_kernel<<<dim3(HDIM / 32, DDIM / 32, NEXP), 256, 0, stream>>>(W1, W1t, DDIM, HDIM);
  transpose_cvt_kernel<<<dim3(DDIM / 32, HDIM / 32, NEXP), 256, 0, stream>>>(W2, W2t, HDIM, DDIM);
  crw_kernel<<<DDIM, 256, 0, stream>>>(ctx_W, r_W, crW);
  cbase_kernel<<<4, 256, 0, stream>>>(ctx_b, q_W, q_b, qual, r_W, r_b, cb);
  router_kernel<<<TOKENS, 256, 0, stream>>>(x, ctx, rn_g, rn_b, cn_g, cn_b, r_W, crW, cb, temp,
                                            token_list, gate_list, counts, aux);
  finalize_kernel<<<1, 256, 0, stream>>>(counts, aux, token_list, gate_list, table,
                                         out + (size_t)TOKENS * DDIM);
  moe_gemm_kernel<0><<<dim3(HDIM / 128, MAX_SLOTS), 256, 0, stream>>>(
      xbf, W1t, b1, token_list, gate_list, table, hbuf, nullptr);
  moe_gemm_kernel<1><<<dim3(DDIM / 128, MAX_SLOTS), 256, 0, stream>>>(
      hbuf, W2t, b2, token_list, gate_list, table, nullptr, out);
}